// Round 6
// baseline (479.001 us; speedup 1.0000x reference)
//
#include <hip/hip_runtime.h>
#include <math.h>

#define N_PTS 8192
#define B_SZ 4
#define SEED_NUM 409
#define THREADS 256
#define LTOT 653  // 65+98+131+163+196
#define N_GROUPS (B_SZ * SEED_NUM)
#define PUB 16  // seed publish cadence (power of 2)

typedef float f2 __attribute__((ext_vector_type(2)));
typedef float f4 __attribute__((ext_vector_type(4)));

// Exact IEEE f32 squared distance, same op order as the reference:
// ((dx*dx + dy*dy) + dz*dz), no FMA contraction.
__device__ __forceinline__ float sqdist(float ax, float ay, float az,
                                        float bx, float by, float bz) {
  float dx = __fsub_rn(ax, bx);
  float dy = __fsub_rn(ay, by);
  float dz = __fsub_rn(az, bz);
  return __fadd_rn(__fadd_rn(__fmul_rn(dx, dx), __fmul_rn(dy, dy)),
                   __fmul_rn(dz, dz));
}

#define FOR16(M) \
  M(0) M(1) M(2) M(3) M(4) M(5) M(6) M(7) \
  M(8) M(9) M(10) M(11) M(12) M(13) M(14) M(15)

// u64 lane-move via two 32-bit DPP ops (ctrl fields must be constant
// expressions -> template params). shr-stages: bound_ctrl=1 (OOB lanes
// read 0 — harmless for max of non-negative keys). bcast stages keep `old`
// in masked-off rows so the subsequent max is a no-op there.
template <int CTRL>
__device__ __forceinline__ unsigned long long dpp_u64_bc1(
    unsigned long long k) {
  const unsigned lo2 = (unsigned)__builtin_amdgcn_update_dpp(
      0, (int)(unsigned)k, CTRL, 0xf, 0xf, true);
  const unsigned hi2 = (unsigned)__builtin_amdgcn_update_dpp(
      0, (int)(unsigned)(k >> 32), CTRL, 0xf, 0xf, true);
  return ((unsigned long long)hi2 << 32) | lo2;
}
template <int CTRL, int ROW_MASK>
__device__ __forceinline__ unsigned long long dpp_u64_keep(
    unsigned long long k) {
  const unsigned lo2 = (unsigned)__builtin_amdgcn_update_dpp(
      (int)(unsigned)k, (int)(unsigned)k, CTRL, ROW_MASK, 0xf, false);
  const unsigned hi2 = (unsigned)__builtin_amdgcn_update_dpp(
      (int)(unsigned)(k >> 32), (int)(unsigned)(k >> 32), CTRL, ROW_MASK, 0xf,
      false);
  return ((unsigned long long)hi2 << 32) | lo2;
}

// LDS union: FPS role needs 136 KB; group role ~21 KB.
struct FpsSmem {
  f4 spts4[N_PTS];               // 128 KiB winner-coord broadcast
  float seedbuf[SEED_NUM * 3];   // deferred/published seed staging
  unsigned long long red[2][4];
};
struct GrpSmem {
  f4 tmp[LTOT];   // pass-1 survivors (x,y,z,tier)
  f4 lpt[LTOT];   // bucket-ordered points
  int tcnt[5], tbase[5], bcnt[5], ccum[5];
  int ntmp, capped;
  int wtot[4];
  double wsum[5][4];
  float ssd[3];
  int islast;
};
union SmemU {
  FpsSmem f;
  GrpSmem g;
};

// ---------------------------------------------------------------------------
// R16: ONE fused kernel. fps used 4/256 CUs for 77% of the runtime while the
// group work (only ~5 groups/us of throughput needed to track seed
// production) ran AFTERWARD on a serialized launch. Fusion + dynamic roles:
//  - roles claimed by atomicAdd in EXECUTION order -> the 4 fps producers are
//    by construction already-running blocks: deadlock-free under any dispatch
//    order (Guideline 16).
//  - fps publishes seeds every PUB=16 iters: atomicExch the 48 floats (RMW ->
//    coherence point) then release-store prog[b]; amortized ~40 cy/iter.
//  - workers: ticket = claim order = ascending seed; acquire-spin (s_sleep)
//    on prog[b], read seed via atomicAdd(p, 0.0f) (returns OLD value:
//    bit-exact read; same proven mechanism as the done-counter finalize).
//  - fps inner loop is the VERBATIM R10 text (ledger: R11 scratch-tree 2.3x,
//    R12 reg-tree +73cy, R13 tail +41cy, R14 pk-asm +420cy — all deviations
//    regressed; do not touch without .s evidence).
//  - counters/sums zeroed by hipMemsetAsync on the stream (replayed per
//    graph iteration), since no single block runs "first" anymore.
// ---------------------------------------------------------------------------
__global__ __launch_bounds__(THREADS, 1) void fused_kernel(
    const float* __restrict__ pcs, float* __restrict__ seeds,
    double* __restrict__ sums /* totS[5] + accA[20] */,
    unsigned int* __restrict__ ctr /* [0]=roleCnt [1]=dcnt [2..5]=prog */,
    float* __restrict__ out) {
#pragma clang fp contract(off)
  const int tid = threadIdx.x;
  __shared__ SmemU sm;
  __shared__ int roleS;
  __shared__ double fin[25];

  if (tid == 0) roleS = (int)atomicAdd(&ctr[0], 1u);
  __syncthreads();
  const int role = roleS;

  if (role < B_SZ) {
    // =============================== FPS ===================================
    const int b = role;
    const int lane = tid & 63, wid = tid >> 6;  // 4 waves
    const float* base = pcs + (size_t)b * N_PTS * 3;
    f4* spts4 = sm.f.spts4;
    float* seedbuf = sm.f.seedbuf;
    auto& red = sm.f.red;

    // pair j holds points i0 = tid + (2j)*256 and i1 = tid + (2j+1)*256
#define FPS_DECL(j) f2 px##j, py##j, pz##j, md##j;
    FOR16(FPS_DECL)
#undef FPS_DECL

#define FPS_INIT(j)                                   \
  {                                                   \
    const int i0 = tid + (2 * (j)) * THREADS;         \
    const int i1 = i0 + THREADS;                      \
    px##j = (f2){base[i0 * 3 + 0], base[i1 * 3 + 0]}; \
    py##j = (f2){base[i0 * 3 + 1], base[i1 * 3 + 1]}; \
    pz##j = (f2){base[i0 * 3 + 2], base[i1 * 3 + 2]}; \
    md##j = (f2){1e10f, 1e10f}; /* ref 1e10 exact */  \
    spts4[i0] = (f4){px##j.x, py##j.x, pz##j.x, 0.f}; \
    spts4[i1] = (f4){px##j.y, py##j.y, pz##j.y, 0.f}; \
  }
    FOR16(FPS_INIT)
#undef FPS_INIT

    // Pin coords in VGPRs (asm results can't be rematerialized from memory).
#define FPS_PIN(j) asm volatile("" : "+v"(px##j), "+v"(py##j), "+v"(pz##j));
    FOR16(FPS_PIN)
#undef FPS_PIN

    float cx = base[0], cy = base[1], cz = base[2];

    for (int s = 0; s < SEED_NUM; ++s) {
      if (tid == 0) {
        seedbuf[s * 3 + 0] = cx;
        seedbuf[s * 3 + 1] = cy;
        seedbuf[s * 3 + 2] = cz;
        if ((s & (PUB - 1)) == (PUB - 1)) {
          // publish seeds [s-PUB+1 .. s]: RMW stores -> coherence point,
          // then release (waits vmcnt) of the progress counter.
          const int s0 = s - (PUB - 1);
          float* sg = seeds + ((size_t)b * SEED_NUM + s0) * 3;
          for (int i = 0; i < PUB * 3; ++i)
            atomicExch(&sg[i], seedbuf[s0 * 3 + i]);
          __hip_atomic_store(&ctr[2 + b], (unsigned)(s + 1),
                             __ATOMIC_RELEASE, __HIP_MEMORY_SCOPE_AGENT);
        }
      }
      const f2 ccx = (f2){cx, cx}, ccy = (f2){cy, cy}, ccz = (f2){cz, cz};
      float bv = -1.0f;
      int bi = 0;
      // ascending index order + strict '>' keeps the first index on ties.
#define FPS_UPD(j)                                                  \
  {                                                                 \
    const f2 dx = px##j - ccx;                                      \
    const f2 dy = py##j - ccy;                                      \
    const f2 dz = pz##j - ccz;                                      \
    const f2 t0 = dx * dx;                                          \
    const f2 t1 = dy * dy;                                          \
    const f2 t2 = dz * dz;                                          \
    const f2 d2 = (t0 + t1) + t2;                                   \
    const f2 m = __builtin_elementwise_min(md##j, d2);              \
    md##j = m;                                                      \
    if (m.x > bv) { bv = m.x; bi = tid + (2 * (j)) * THREADS; }     \
    if (m.y > bv) { bv = m.y; bi = tid + (2 * (j) + 1) * THREADS; } \
  }
      FOR16(FPS_UPD)
#undef FPS_UPD
      // packed argmax key: bv >= 0 so f32 bits are monotone; u64 max ==
      // (max value, tie -> min index) == jnp.argmax semantics.
      unsigned long long key =
          ((unsigned long long)__float_as_uint(bv) << 32) |
          (unsigned long long)(unsigned)(N_PTS - 1 - bi);
      unsigned long long o;
      o = dpp_u64_bc1<0x111>(key);        key = (o > key) ? o : key;  // shr 1
      o = dpp_u64_bc1<0x112>(key);        key = (o > key) ? o : key;  // shr 2
      o = dpp_u64_bc1<0x114>(key);        key = (o > key) ? o : key;  // shr 4
      o = dpp_u64_bc1<0x118>(key);        key = (o > key) ? o : key;  // shr 8
      o = dpp_u64_keep<0x142, 0xa>(key);  key = (o > key) ? o : key;  // bc15
      o = dpp_u64_keep<0x143, 0xc>(key);  key = (o > key) ? o : key;  // bc31
      if (lane == 63) red[s & 1][wid] = key;
      __syncthreads();
      unsigned long long kmax = red[s & 1][0];
#pragma unroll
      for (int w = 1; w < 4; ++w) {
        const unsigned long long t = red[s & 1][w];
        kmax = (t > kmax) ? t : kmax;
      }
      const int ci = N_PTS - 1 - (int)(unsigned)(kmax & 0xffffffffull);
      const f4 c = spts4[ci];  // one ds_read_b128, same-address broadcast
      cx = c.x;
      cy = c.y;
      cz = c.z;
    }

    // final partial publish: seeds [400..408]
    if (tid == 0) {
      const int s0 = SEED_NUM & ~(PUB - 1);  // 400
      float* sg = seeds + ((size_t)b * SEED_NUM + s0) * 3;
      for (int i = 0; i < (SEED_NUM - s0) * 3; ++i)
        atomicExch(&sg[i], seedbuf[s0 * 3 + i]);
      __hip_atomic_store(&ctr[2 + b], (unsigned)SEED_NUM, __ATOMIC_RELEASE,
                         __HIP_MEMORY_SCOPE_AGENT);
    }
    return;
  }

  // ============================ GROUP worker ===============================
  const int tk = role - B_SZ;
  if (tk >= N_GROUPS) return;
  const int s = tk >> 2;   // ascending ticket -> ascending seed
  const int b = tk & 3;
  const int lane = tid & 63, wid = tid >> 6;

  const int Kc[5] = {65, 98, 131, 163, 196};
  const int off[5] = {0, 65, 163, 294, 457};  // fallback layout only
  const double Pd[5] = {0.004, 0.006, 0.008, 0.01, 0.012};
  float r2c[5], expnf[5], expdc[5];
#pragma unroll
  for (int p = 0; p < 5; ++p) {
    const double pd = Pd[p];
    const double rd = sqrt(pd);
    r2c[p] = (float)(rd * rd);                     // weak f32 cast of r*r
    const double expn_d = 8192.0 * pd;
    expnf[p] = (float)expn_d;
    expdc[p] = sqrtf((float)(M_PI / expn_d * pd));  // expect_dis
  }

  const float* base = pcs + (size_t)b * N_PTS * 3;
  f4* tmp = sm.g.tmp;
  f4* lpt = sm.g.lpt;
  int* tcnt = sm.g.tcnt;
  int* tbase = sm.g.tbase;
  int* bcnt = sm.g.bcnt;
  int* ccum = sm.g.ccum;
  int* wtot = sm.g.wtot;
  double (*wsum)[4] = sm.g.wsum;
  double* totS = sums;
  double* accA = sums + 5;

  if (tid < 5) { tcnt[tid] = 0; bcnt[tid] = 0; }
  if (tid == 6) sm.g.ntmp = 0;
  if (tid == 0) {
    // wait for seed s of batch b, then device-coherent RMW read
    while (__hip_atomic_load(&ctr[2 + b], __ATOMIC_ACQUIRE,
                             __HIP_MEMORY_SCOPE_AGENT) <= (unsigned)s)
      __builtin_amdgcn_s_sleep(16);
    const size_t so = ((size_t)b * SEED_NUM + s) * 3;
    sm.g.ssd[0] = atomicAdd(&seeds[so + 0], 0.0f);  // returns OLD: exact
    sm.g.ssd[1] = atomicAdd(&seeds[so + 1], 0.0f);
    sm.g.ssd[2] = atomicAdd(&seeds[so + 2], 0.0f);
  }
  __syncthreads();
  const float sx = sm.g.ssd[0], sy = sm.g.ssd[1], sz = sm.g.ssd[2];

  // ---- pass 1: vectorized scan, tier-count + unordered survivor append ----
  const float r2max = r2c[4];
  const f4* base4 = (const f4*)base;  // 12B-packed points, 16B-aligned base
#define PROC(X, Y, Z)                                              \
  {                                                                \
    const float d2 = sqdist((X), (Y), (Z), sx, sy, sz);            \
    if (d2 < r2max) {                                              \
      const int tier = (d2 < r2c[0]) ? 0                           \
                       : (d2 < r2c[1]) ? 1                         \
                       : (d2 < r2c[2]) ? 2                         \
                       : (d2 < r2c[3]) ? 3 : 4;                    \
      atomicAdd(&tcnt[tier], 1);                                   \
      const int pos = atomicAdd(&sm.g.ntmp, 1);                    \
      if (pos < LTOT) tmp[pos] = (f4){(X), (Y), (Z), (float)tier}; \
    }                                                              \
  }
  for (int it = 0; it < 8; ++it) {
    const int q = it * 256 + tid;  // quad-of-points index, 0..2047
    const f4 v0 = base4[q * 3 + 0];
    const f4 v1 = base4[q * 3 + 1];
    const f4 v2 = base4[q * 3 + 2];
    PROC(v0.x, v0.y, v0.z)
    PROC(v0.w, v1.x, v1.y)
    PROC(v1.z, v1.w, v2.x)
    PROC(v2.y, v2.z, v2.w)
  }
#undef PROC
  __syncthreads();

  // ---- prefix + cap check ----
  if (tid == 0) {
    int acc = 0, cap = 0;
#pragma unroll
    for (int t = 0; t < 5; ++t) {
      tbase[t] = acc;
      acc += tcnt[t];
      ccum[t] = acc;
    }
#pragma unroll
    for (int p = 0; p < 5; ++p) cap |= (ccum[p] > Kc[p]) ? 1 : 0;
    sm.g.capped = cap;
  }
  __syncthreads();

  // ---- pass 2: scatter survivors to tier-bucket positions ----
  const int nt = min(sm.g.ntmp, LTOT);
  for (int t = tid; t < nt; t += 256) {
    const f4 e = tmp[t];
    const int tier = (int)e.w;
    const int pos = tbase[tier] + atomicAdd(&bcnt[tier], 1);
    if (pos < LTOT) lpt[pos] = (f4){e.x, e.y, e.z, 0.f};
  }
  __syncthreads();

  if (!sm.g.capped) {
    // ---- segmented KNN: one pass over [0, c4) per row, snapshots at
    //      bucket boundaries give the two-min of every prefix list ----
    const int c0 = ccum[0], c1 = ccum[1], c2 = ccum[2], c3 = ccum[3],
              c4 = ccum[4];
    double lS0 = 0.0, lS1 = 0.0, lS2 = 0.0, lS3 = 0.0, lS4 = 0.0;
    for (int r0 = 0; r0 < c4; r0 += 64) {
      const int row = r0 + (tid >> 2);
      const int sub = tid & 3;
      const bool rok = row < c4;
      const f4 pi = lpt[rok ? row : 0];
      float m1 = INFINITY, m2 = INFINITY;
      int j = sub;
#define SEGMENT(CP, EDP, LSP)                                        \
  {                                                                  \
    for (; j < (CP); j += 4) {                                       \
      const f4 pj = lpt[j];                                          \
      const float d2 = sqdist(pi.x, pi.y, pi.z, pj.x, pj.y, pj.z);   \
      if (d2 < m1) { m2 = m1; m1 = d2; }                             \
      else if (d2 < m2) { m2 = d2; }                                 \
    }                                                                \
    float s1 = m1, s2 = m2;                                          \
    {                                                                \
      const float o1 = __shfl_xor(s1, 1), o2 = __shfl_xor(s2, 1);    \
      const float lo = fminf(s1, o1), hi = fmaxf(s1, o1);            \
      s2 = fminf(fminf(s2, o2), hi); s1 = lo;                        \
    }                                                                \
    {                                                                \
      const float o1 = __shfl_xor(s1, 2), o2 = __shfl_xor(s2, 2);    \
      const float lo = fminf(s1, o1), hi = fmaxf(s1, o1);            \
      s2 = fminf(fminf(s2, o2), hi); s1 = lo;                        \
    }                                                                \
    if (rok && sub == 0 && row < (CP)) {                             \
      const float nn2 = (s2 > 1e37f) ? 0.0f : s2; /* inf -> 0 */     \
      const float nnd = (nn2 > 0.0f) ? sqrtf(nn2) : 0.0f;            \
      const float diff = __fsub_rn(nnd, (EDP));                      \
      const float clut = __fdiv_rn(__fmul_rn(diff, diff),            \
                                   __fadd_rn((EDP), 1e-12f));        \
      LSP += (double)clut;                                           \
    }                                                                \
  }
      SEGMENT(c0, expdc[0], lS0)
      SEGMENT(c1, expdc[1], lS1)
      SEGMENT(c2, expdc[2], lS2)
      SEGMENT(c3, expdc[3], lS3)
      SEGMENT(c4, expdc[4], lS4)
#undef SEGMENT
    }
#define RED(LSP, P)                                          \
  {                                                          \
    double v = (LSP);                                        \
    for (int o = 32; o > 0; o >>= 1) v += __shfl_down(v, o); \
    if (lane == 0) wsum[(P)][wid] = v;                       \
  }
    RED(lS0, 0) RED(lS1, 1) RED(lS2, 2) RED(lS3, 3) RED(lS4, 4)
#undef RED
  } else {
    // ---- measure-zero fallback: ordered per-p lists + old per-p KNN ----
#pragma unroll
    for (int p = 0; p < 5; ++p) {
      int run = 0;
      for (int base_i = 0; base_i < N_PTS; base_i += 256) {
        const int i = base_i + tid;
        const float x = base[i * 3 + 0];
        const float y = base[i * 3 + 1];
        const float z = base[i * 3 + 2];
        const float d2 = sqdist(x, y, z, sx, sy, sz);
        const bool valid = d2 < r2c[p];
        const unsigned long long m = __ballot(valid);
        if (lane == 0) wtot[wid] = __popcll(m);
        __syncthreads();
        int pos = run + __popcll(m & ((1ull << lane) - 1ull));
        for (int w = 0; w < wid; ++w) pos += wtot[w];
        if (valid && pos < Kc[p]) {
          lpt[off[p] + pos] = (f4){x, y, z, 0.f};
        }
        run += wtot[0] + wtot[1] + wtot[2] + wtot[3];
        __syncthreads();
      }
    }
#pragma unroll
    for (int p = 0; p < 5; ++p) {
      const int gn = min(ccum[p], Kc[p]);
      const float ed = expdc[p];
      const int lb = off[p];
      double localS = 0.0;
      for (int r0 = 0; r0 < gn; r0 += 64) {
        const int row = r0 + (tid >> 2);
        const int sub = tid & 3;
        float m1 = INFINITY, m2 = INFINITY;
        if (row < gn) {
          const f4 pi = lpt[lb + row];
          for (int j = sub; j < gn; j += 4) {
            const f4 pj = lpt[lb + j];
            const float d2 = sqdist(pi.x, pi.y, pi.z, pj.x, pj.y, pj.z);
            if (d2 < m1) { m2 = m1; m1 = d2; }
            else if (d2 < m2) { m2 = d2; }
          }
        }
#pragma unroll
        for (int d = 1; d <= 2; d <<= 1) {
          const float om1 = __shfl_xor(m1, d);
          const float om2 = __shfl_xor(m2, d);
          const float lo = fminf(m1, om1);
          const float hi = fmaxf(m1, om1);
          m2 = fminf(fminf(m2, om2), hi);
          m1 = lo;
        }
        if (row < gn && sub == 0) {
          const float nn2 = (m2 > 1e37f) ? 0.0f : m2;
          const float nnd = (nn2 > 0.0f) ? sqrtf(nn2) : 0.0f;
          const float diff = __fsub_rn(nnd, ed);
          const float clut = __fdiv_rn(__fmul_rn(diff, diff),
                                       __fadd_rn(ed, 1e-12f));
          localS += (double)clut;
        }
      }
#pragma unroll
      for (int o = 32; o > 0; o >>= 1) localS += __shfl_down(localS, o);
      if (lane == 0) wsum[p][wid] = localS;
      __syncthreads();
    }
  }
  __syncthreads();

  // 10 parallel device atomics: threads 0-4 -> totS, threads 5-9 -> accA.
  if (tid < 5) {
    const double S = wsum[tid][0] + wsum[tid][1] + wsum[tid][2] + wsum[tid][3];
    atomicAdd(&totS[tid], S);
  } else if (tid < 10) {
    const int p = tid - 5;
    const int gn = min(ccum[p], Kc[p]);
    const float gf = (float)gn;
    const float dd = __fsub_rn(gf, expnf[p]);
    const float imb = __fdiv_rn(__fmul_rn(dd, dd), expnf[p]);
    atomicAdd(&accA[p * 4 + b], (double)imb / (double)gf);
  }

  // ---- fused finalize: last group block computes the loss ----
  __syncthreads();  // drains vmcnt -> this block's atomics are at L2
  if (tid == 0) {
    __threadfence();
    const unsigned int old = atomicAdd(&ctr[1], 1u);
    sm.g.islast = (old == (unsigned int)(N_GROUPS - 1)) ? 1 : 0;
  }
  __syncthreads();
  if (sm.g.islast) {
    if (tid < 25) {
      // device-scope atomic read (add 0.0) -> sees all blocks' additions
      double* src = (tid < 5) ? &totS[tid] : &accA[tid - 5];
      fin[tid] = atomicAdd(src, 0.0);
    }
    __syncthreads();
    if (tid < B_SZ) {
      double acc = 0.0;
#pragma unroll
      for (int p = 0; p < 5; ++p)
        acc += fin[p] * (fin[5 + p * 4 + tid] / (double)SEED_NUM);
      out[tid] = (float)(acc / 5.0);
    }
  }
}

extern "C" void kernel_launch(void* const* d_in, const int* in_sizes, int n_in,
                              void* d_out, int out_size, void* d_ws,
                              size_t ws_size, hipStream_t stream) {
  (void)in_sizes; (void)n_in; (void)out_size; (void)ws_size;
  const float* pcs = (const float*)d_in[0];
  float* out = (float*)d_out;

  // ws layout: seeds (B*409*3 f32 = 19632 B), sums (25 doubles = 200 B),
  // counters (6 u32 = 24 B: roleCnt, dcnt, prog[4]).
  float* seeds = (float*)d_ws;
  double* sums = (double*)((char*)d_ws + 19632);
  unsigned int* ctr = (unsigned int*)((char*)d_ws + 19632 + 200);

  // zero sums + counters every invocation (graph-capturable stream op)
  hipMemsetAsync((char*)d_ws + 19632, 0, 200 + 24, stream);
  fused_kernel<<<B_SZ + N_GROUPS, THREADS, 0, stream>>>(pcs, seeds, sums, ctr,
                                                        out);
}

// Round 7
// 444.108 us; speedup vs baseline: 1.0786x; 1.0786x over previous
//
#include <hip/hip_runtime.h>
#include <math.h>

#define N_PTS 8192
#define B_SZ 4
#define SEED_NUM 409
#define THREADS 256
#define LTOT 653  // 65+98+131+163+196
#define N_GROUPS (B_SZ * SEED_NUM)
#define PUB 16  // seed publish cadence (power of 2)

// padded counter layout (u32 indices): 128 B apart
#define CTR_ROLE 0
#define CTR_DONE 32
#define CTR_PROG(b) (64 + 32 * (b))

typedef float f2 __attribute__((ext_vector_type(2)));
typedef float f4 __attribute__((ext_vector_type(4)));

// Exact IEEE f32 squared distance, same op order as the reference:
// ((dx*dx + dy*dy) + dz*dz), no FMA contraction.
__device__ __forceinline__ float sqdist(float ax, float ay, float az,
                                        float bx, float by, float bz) {
  float dx = __fsub_rn(ax, bx);
  float dy = __fsub_rn(ay, by);
  float dz = __fsub_rn(az, bz);
  return __fadd_rn(__fadd_rn(__fmul_rn(dx, dx), __fmul_rn(dy, dy)),
                   __fmul_rn(dz, dz));
}

#define FOR16(M) \
  M(0) M(1) M(2) M(3) M(4) M(5) M(6) M(7) \
  M(8) M(9) M(10) M(11) M(12) M(13) M(14) M(15)

// u64 lane-move via two 32-bit DPP ops (ctrl fields must be constant
// expressions -> template params). shr-stages: bound_ctrl=1 (OOB lanes
// read 0 — harmless for max of non-negative keys). bcast stages keep `old`
// in masked-off rows so the subsequent max is a no-op there.
template <int CTRL>
__device__ __forceinline__ unsigned long long dpp_u64_bc1(
    unsigned long long k) {
  const unsigned lo2 = (unsigned)__builtin_amdgcn_update_dpp(
      0, (int)(unsigned)k, CTRL, 0xf, 0xf, true);
  const unsigned hi2 = (unsigned)__builtin_amdgcn_update_dpp(
      0, (int)(unsigned)(k >> 32), CTRL, 0xf, 0xf, true);
  return ((unsigned long long)hi2 << 32) | lo2;
}
template <int CTRL, int ROW_MASK>
__device__ __forceinline__ unsigned long long dpp_u64_keep(
    unsigned long long k) {
  const unsigned lo2 = (unsigned)__builtin_amdgcn_update_dpp(
      (int)(unsigned)k, (int)(unsigned)k, CTRL, ROW_MASK, 0xf, false);
  const unsigned hi2 = (unsigned)__builtin_amdgcn_update_dpp(
      (int)(unsigned)(k >> 32), (int)(unsigned)(k >> 32), CTRL, ROW_MASK, 0xf,
      false);
  return ((unsigned long long)hi2 << 32) | lo2;
}

// LDS union: FPS role needs 136 KB; group role ~21 KB.
struct FpsSmem {
  f4 spts4[N_PTS];               // 128 KiB winner-coord broadcast
  float seedbuf[SEED_NUM * 3];   // published-seed staging
  unsigned long long red[2][4];
};
struct GrpSmem {
  f4 tmp[LTOT];   // pass-1 survivors (x,y,z,tier)
  f4 lpt[LTOT];   // bucket-ordered points
  int tcnt[5], tbase[5], bcnt[5], ccum[5];
  int ntmp, capped;
  int wtot[4];
  double wsum[5][4];
  float ssd[3];
  int islast;
};
union SmemU {
  FpsSmem f;
  GrpSmem g;
};

// ---------------------------------------------------------------------------
// R17: fix the R16 fusion overheads that put ~590 cy/iter on the fps critical
// path (444 vs 333 solo):
//  (1) publish was 48 SERIAL tid0 atomicExch + vmcnt(0) release BEFORE the
//      iteration barrier. Now: lanes tid<48 issue ONE wave-wide
//      global_atomic_swap (issued BEFORE FPS_UPD -> L3 latency hides under
//      compute; drains at the EXISTING barrier); the prog release store moves
//      AFTER the barrier where wave0's vmcnt is already 0 (free waitcnt).
//      Publish covers the PREVIOUS 16 seeds (s%16==0) so every published
//      seedbuf entry is barrier-ordered before its LDS read.
//  (2) roleCnt/dcnt/prog[0..3] shared ONE cacheline: claims + done-RMWs +
//      ~2000 pollers + producer release stores all fought for it. Now each
//      counter sits on its own 128 B line.
//  (3) pollers: s_sleep(32) (~2k cy) — detection latency << publish cadence.
// fps inner loop remains the VERBATIM R10 text (ledger: R11 scratch 2.3x,
// R12 tree +73cy, R13 tail +41cy, R14 pk-asm +420cy — do not touch).
// ---------------------------------------------------------------------------
__global__ __launch_bounds__(THREADS, 1) void fused_kernel(
    const float* __restrict__ pcs, float* __restrict__ seeds,
    double* __restrict__ sums /* totS[5] + accA[20] */,
    unsigned int* __restrict__ ctr /* padded, see CTR_* */,
    float* __restrict__ out) {
#pragma clang fp contract(off)
  const int tid = threadIdx.x;
  __shared__ SmemU sm;
  __shared__ int roleS;
  __shared__ double fin[25];

  if (tid == 0) roleS = (int)atomicAdd(&ctr[CTR_ROLE], 1u);
  __syncthreads();
  const int role = roleS;

  if (role < B_SZ) {
    // =============================== FPS ===================================
    const int b = role;
    const int lane = tid & 63, wid = tid >> 6;  // 4 waves
    const float* base = pcs + (size_t)b * N_PTS * 3;
    f4* spts4 = sm.f.spts4;
    float* seedbuf = sm.f.seedbuf;
    auto& red = sm.f.red;
    float* sgb = seeds + (size_t)b * SEED_NUM * 3;

    // pair j holds points i0 = tid + (2j)*256 and i1 = tid + (2j+1)*256
#define FPS_DECL(j) f2 px##j, py##j, pz##j, md##j;
    FOR16(FPS_DECL)
#undef FPS_DECL

#define FPS_INIT(j)                                   \
  {                                                   \
    const int i0 = tid + (2 * (j)) * THREADS;         \
    const int i1 = i0 + THREADS;                      \
    px##j = (f2){base[i0 * 3 + 0], base[i1 * 3 + 0]}; \
    py##j = (f2){base[i0 * 3 + 1], base[i1 * 3 + 1]}; \
    pz##j = (f2){base[i0 * 3 + 2], base[i1 * 3 + 2]}; \
    md##j = (f2){1e10f, 1e10f}; /* ref 1e10 exact */  \
    spts4[i0] = (f4){px##j.x, py##j.x, pz##j.x, 0.f}; \
    spts4[i1] = (f4){px##j.y, py##j.y, pz##j.y, 0.f}; \
  }
    FOR16(FPS_INIT)
#undef FPS_INIT

    // Pin coords in VGPRs (asm results can't be rematerialized from memory).
#define FPS_PIN(j) asm volatile("" : "+v"(px##j), "+v"(py##j), "+v"(pz##j));
    FOR16(FPS_PIN)
#undef FPS_PIN

    float cx = base[0], cy = base[1], cz = base[2];

    for (int s = 0; s < SEED_NUM; ++s) {
      if (tid == 0) {
        seedbuf[s * 3 + 0] = cx;
        seedbuf[s * 3 + 1] = cy;
        seedbuf[s * 3 + 2] = cz;
      }
      const bool pubit = (s != 0) && ((s & (PUB - 1)) == 0);
      if (pubit && tid < PUB * 3) {
        // one wave-wide atomic swap, issued before compute: latency hides
        // under FPS_UPD; drains at this iteration's barrier.
        const float v = seedbuf[(s - PUB) * 3 + tid];
        atomicExch(&sgb[(s - PUB) * 3 + tid], v);
      }
      const f2 ccx = (f2){cx, cx}, ccy = (f2){cy, cy}, ccz = (f2){cz, cz};
      float bv = -1.0f;
      int bi = 0;
      // ascending index order + strict '>' keeps the first index on ties.
#define FPS_UPD(j)                                                  \
  {                                                                 \
    const f2 dx = px##j - ccx;                                      \
    const f2 dy = py##j - ccy;                                      \
    const f2 dz = pz##j - ccz;                                      \
    const f2 t0 = dx * dx;                                          \
    const f2 t1 = dy * dy;                                          \
    const f2 t2 = dz * dz;                                          \
    const f2 d2 = (t0 + t1) + t2;                                   \
    const f2 m = __builtin_elementwise_min(md##j, d2);              \
    md##j = m;                                                      \
    if (m.x > bv) { bv = m.x; bi = tid + (2 * (j)) * THREADS; }     \
    if (m.y > bv) { bv = m.y; bi = tid + (2 * (j) + 1) * THREADS; } \
  }
      FOR16(FPS_UPD)
#undef FPS_UPD
      // packed argmax key: bv >= 0 so f32 bits are monotone; u64 max ==
      // (max value, tie -> min index) == jnp.argmax semantics.
      unsigned long long key =
          ((unsigned long long)__float_as_uint(bv) << 32) |
          (unsigned long long)(unsigned)(N_PTS - 1 - bi);
      unsigned long long o;
      o = dpp_u64_bc1<0x111>(key);        key = (o > key) ? o : key;  // shr 1
      o = dpp_u64_bc1<0x112>(key);        key = (o > key) ? o : key;  // shr 2
      o = dpp_u64_bc1<0x114>(key);        key = (o > key) ? o : key;  // shr 4
      o = dpp_u64_bc1<0x118>(key);        key = (o > key) ? o : key;  // shr 8
      o = dpp_u64_keep<0x142, 0xa>(key);  key = (o > key) ? o : key;  // bc15
      o = dpp_u64_keep<0x143, 0xc>(key);  key = (o > key) ? o : key;  // bc31
      if (lane == 63) red[s & 1][wid] = key;
      __syncthreads();
      // post-barrier: wave0's vmcnt==0 -> the release's waitcnt is free.
      if (pubit && tid == 0) {
        __hip_atomic_store(&ctr[CTR_PROG(b)], (unsigned)s, __ATOMIC_RELEASE,
                           __HIP_MEMORY_SCOPE_AGENT);
      }
      unsigned long long kmax = red[s & 1][0];
#pragma unroll
      for (int w = 1; w < 4; ++w) {
        const unsigned long long t = red[s & 1][w];
        kmax = (t > kmax) ? t : kmax;
      }
      const int ci = N_PTS - 1 - (int)(unsigned)(kmax & 0xffffffffull);
      const f4 c = spts4[ci];  // one ds_read_b128, same-address broadcast
      cx = c.x;
      cy = c.y;
      cz = c.z;
    }

    // final publish: seeds [(409 & ~15) - 16 .. 408] = [384 .. 408]
    // (the s=400 pub covered up to 399 only if 400%16==0 — it is; so publish
    //  the remaining 400..408 here: 27 floats, one partial wave op.)
    {
      const int s0 = SEED_NUM & ~(PUB - 1);  // 400
      const int nfl = (SEED_NUM - s0) * 3;   // 27
      if (tid < nfl) {
        const float v = seedbuf[s0 * 3 + tid];
        atomicExch(&sgb[s0 * 3 + tid], v);
      }
      __syncthreads();  // drains the swap before the release store
      if (tid == 0)
        __hip_atomic_store(&ctr[CTR_PROG(b)], (unsigned)SEED_NUM,
                           __ATOMIC_RELEASE, __HIP_MEMORY_SCOPE_AGENT);
    }
    return;
  }

  // ============================ GROUP worker ===============================
  const int tk = role - B_SZ;
  if (tk >= N_GROUPS) return;
  const int s = tk >> 2;   // ascending ticket -> ascending seed
  const int b = tk & 3;
  const int lane = tid & 63, wid = tid >> 6;

  const int Kc[5] = {65, 98, 131, 163, 196};
  const int off[5] = {0, 65, 163, 294, 457};  // fallback layout only
  const double Pd[5] = {0.004, 0.006, 0.008, 0.01, 0.012};
  float r2c[5], expnf[5], expdc[5];
#pragma unroll
  for (int p = 0; p < 5; ++p) {
    const double pd = Pd[p];
    const double rd = sqrt(pd);
    r2c[p] = (float)(rd * rd);                     // weak f32 cast of r*r
    const double expn_d = 8192.0 * pd;
    expnf[p] = (float)expn_d;
    expdc[p] = sqrtf((float)(M_PI / expn_d * pd));  // expect_dis
  }

  const float* base = pcs + (size_t)b * N_PTS * 3;
  f4* tmp = sm.g.tmp;
  f4* lpt = sm.g.lpt;
  int* tcnt = sm.g.tcnt;
  int* tbase = sm.g.tbase;
  int* bcnt = sm.g.bcnt;
  int* ccum = sm.g.ccum;
  int* wtot = sm.g.wtot;
  double (*wsum)[4] = sm.g.wsum;
  double* totS = sums;
  double* accA = sums + 5;

  if (tid < 5) { tcnt[tid] = 0; bcnt[tid] = 0; }
  if (tid == 6) sm.g.ntmp = 0;
  if (tid == 0) {
    // wait for seed s of batch b, then device-coherent RMW read
    while (__hip_atomic_load(&ctr[CTR_PROG(b)], __ATOMIC_ACQUIRE,
                             __HIP_MEMORY_SCOPE_AGENT) <= (unsigned)s)
      __builtin_amdgcn_s_sleep(32);
    const size_t so = ((size_t)b * SEED_NUM + s) * 3;
    sm.g.ssd[0] = atomicAdd(&seeds[so + 0], 0.0f);  // returns OLD: exact
    sm.g.ssd[1] = atomicAdd(&seeds[so + 1], 0.0f);
    sm.g.ssd[2] = atomicAdd(&seeds[so + 2], 0.0f);
  }
  __syncthreads();
  const float sx = sm.g.ssd[0], sy = sm.g.ssd[1], sz = sm.g.ssd[2];

  // ---- pass 1: vectorized scan, tier-count + unordered survivor append ----
  const float r2max = r2c[4];
  const f4* base4 = (const f4*)base;  // 12B-packed points, 16B-aligned base
#define PROC(X, Y, Z)                                              \
  {                                                                \
    const float d2 = sqdist((X), (Y), (Z), sx, sy, sz);            \
    if (d2 < r2max) {                                              \
      const int tier = (d2 < r2c[0]) ? 0                           \
                       : (d2 < r2c[1]) ? 1                         \
                       : (d2 < r2c[2]) ? 2                         \
                       : (d2 < r2c[3]) ? 3 : 4;                    \
      atomicAdd(&tcnt[tier], 1);                                   \
      const int pos = atomicAdd(&sm.g.ntmp, 1);                    \
      if (pos < LTOT) tmp[pos] = (f4){(X), (Y), (Z), (float)tier}; \
    }                                                              \
  }
  for (int it = 0; it < 8; ++it) {
    const int q = it * 256 + tid;  // quad-of-points index, 0..2047
    const f4 v0 = base4[q * 3 + 0];
    const f4 v1 = base4[q * 3 + 1];
    const f4 v2 = base4[q * 3 + 2];
    PROC(v0.x, v0.y, v0.z)
    PROC(v0.w, v1.x, v1.y)
    PROC(v1.z, v1.w, v2.x)
    PROC(v2.y, v2.z, v2.w)
  }
#undef PROC
  __syncthreads();

  // ---- prefix + cap check ----
  if (tid == 0) {
    int acc = 0, cap = 0;
#pragma unroll
    for (int t = 0; t < 5; ++t) {
      tbase[t] = acc;
      acc += tcnt[t];
      ccum[t] = acc;
    }
#pragma unroll
    for (int p = 0; p < 5; ++p) cap |= (ccum[p] > Kc[p]) ? 1 : 0;
    sm.g.capped = cap;
  }
  __syncthreads();

  // ---- pass 2: scatter survivors to tier-bucket positions ----
  const int nt = min(sm.g.ntmp, LTOT);
  for (int t = tid; t < nt; t += 256) {
    const f4 e = tmp[t];
    const int tier = (int)e.w;
    const int pos = tbase[tier] + atomicAdd(&bcnt[tier], 1);
    if (pos < LTOT) lpt[pos] = (f4){e.x, e.y, e.z, 0.f};
  }
  __syncthreads();

  if (!sm.g.capped) {
    // ---- segmented KNN: one pass over [0, c4) per row, snapshots at
    //      bucket boundaries give the two-min of every prefix list ----
    const int c0 = ccum[0], c1 = ccum[1], c2 = ccum[2], c3 = ccum[3],
              c4 = ccum[4];
    double lS0 = 0.0, lS1 = 0.0, lS2 = 0.0, lS3 = 0.0, lS4 = 0.0;
    for (int r0 = 0; r0 < c4; r0 += 64) {
      const int row = r0 + (tid >> 2);
      const int sub = tid & 3;
      const bool rok = row < c4;
      const f4 pi = lpt[rok ? row : 0];
      float m1 = INFINITY, m2 = INFINITY;
      int j = sub;
#define SEGMENT(CP, EDP, LSP)                                        \
  {                                                                  \
    for (; j < (CP); j += 4) {                                       \
      const f4 pj = lpt[j];                                          \
      const float d2 = sqdist(pi.x, pi.y, pi.z, pj.x, pj.y, pj.z);   \
      if (d2 < m1) { m2 = m1; m1 = d2; }                             \
      else if (d2 < m2) { m2 = d2; }                                 \
    }                                                                \
    float s1 = m1, s2 = m2;                                          \
    {                                                                \
      const float o1 = __shfl_xor(s1, 1), o2 = __shfl_xor(s2, 1);    \
      const float lo = fminf(s1, o1), hi = fmaxf(s1, o1);            \
      s2 = fminf(fminf(s2, o2), hi); s1 = lo;                        \
    }                                                                \
    {                                                                \
      const float o1 = __shfl_xor(s1, 2), o2 = __shfl_xor(s2, 2);    \
      const float lo = fminf(s1, o1), hi = fmaxf(s1, o1);            \
      s2 = fminf(fminf(s2, o2), hi); s1 = lo;                        \
    }                                                                \
    if (rok && sub == 0 && row < (CP)) {                             \
      const float nn2 = (s2 > 1e37f) ? 0.0f : s2; /* inf -> 0 */     \
      const float nnd = (nn2 > 0.0f) ? sqrtf(nn2) : 0.0f;            \
      const float diff = __fsub_rn(nnd, (EDP));                      \
      const float clut = __fdiv_rn(__fmul_rn(diff, diff),            \
                                   __fadd_rn((EDP), 1e-12f));        \
      LSP += (double)clut;                                           \
    }                                                                \
  }
      SEGMENT(c0, expdc[0], lS0)
      SEGMENT(c1, expdc[1], lS1)
      SEGMENT(c2, expdc[2], lS2)
      SEGMENT(c3, expdc[3], lS3)
      SEGMENT(c4, expdc[4], lS4)
#undef SEGMENT
    }
#define RED(LSP, P)                                          \
  {                                                          \
    double v = (LSP);                                        \
    for (int o = 32; o > 0; o >>= 1) v += __shfl_down(v, o); \
    if (lane == 0) wsum[(P)][wid] = v;                       \
  }
    RED(lS0, 0) RED(lS1, 1) RED(lS2, 2) RED(lS3, 3) RED(lS4, 4)
#undef RED
  } else {
    // ---- measure-zero fallback: ordered per-p lists + old per-p KNN ----
#pragma unroll
    for (int p = 0; p < 5; ++p) {
      int run = 0;
      for (int base_i = 0; base_i < N_PTS; base_i += 256) {
        const int i = base_i + tid;
        const float x = base[i * 3 + 0];
        const float y = base[i * 3 + 1];
        const float z = base[i * 3 + 2];
        const float d2 = sqdist(x, y, z, sx, sy, sz);
        const bool valid = d2 < r2c[p];
        const unsigned long long m = __ballot(valid);
        if (lane == 0) wtot[wid] = __popcll(m);
        __syncthreads();
        int pos = run + __popcll(m & ((1ull << lane) - 1ull));
        for (int w = 0; w < wid; ++w) pos += wtot[w];
        if (valid && pos < Kc[p]) {
          lpt[off[p] + pos] = (f4){x, y, z, 0.f};
        }
        run += wtot[0] + wtot[1] + wtot[2] + wtot[3];
        __syncthreads();
      }
    }
#pragma unroll
    for (int p = 0; p < 5; ++p) {
      const int gn = min(ccum[p], Kc[p]);
      const float ed = expdc[p];
      const int lb = off[p];
      double localS = 0.0;
      for (int r0 = 0; r0 < gn; r0 += 64) {
        const int row = r0 + (tid >> 2);
        const int sub = tid & 3;
        float m1 = INFINITY, m2 = INFINITY;
        if (row < gn) {
          const f4 pi = lpt[lb + row];
          for (int j = sub; j < gn; j += 4) {
            const f4 pj = lpt[lb + j];
            const float d2 = sqdist(pi.x, pi.y, pi.z, pj.x, pj.y, pj.z);
            if (d2 < m1) { m2 = m1; m1 = d2; }
            else if (d2 < m2) { m2 = d2; }
          }
        }
#pragma unroll
        for (int d = 1; d <= 2; d <<= 1) {
          const float om1 = __shfl_xor(m1, d);
          const float om2 = __shfl_xor(m2, d);
          const float lo = fminf(m1, om1);
          const float hi = fmaxf(m1, om1);
          m2 = fminf(fminf(m2, om2), hi);
          m1 = lo;
        }
        if (row < gn && sub == 0) {
          const float nn2 = (m2 > 1e37f) ? 0.0f : m2;
          const float nnd = (nn2 > 0.0f) ? sqrtf(nn2) : 0.0f;
          const float diff = __fsub_rn(nnd, ed);
          const float clut = __fdiv_rn(__fmul_rn(diff, diff),
                                       __fadd_rn(ed, 1e-12f));
          localS += (double)clut;
        }
      }
#pragma unroll
      for (int o = 32; o > 0; o >>= 1) localS += __shfl_down(localS, o);
      if (lane == 0) wsum[p][wid] = localS;
      __syncthreads();
    }
  }
  __syncthreads();

  // 10 parallel device atomics: threads 0-4 -> totS, threads 5-9 -> accA.
  if (tid < 5) {
    const double S = wsum[tid][0] + wsum[tid][1] + wsum[tid][2] + wsum[tid][3];
    atomicAdd(&totS[tid], S);
  } else if (tid < 10) {
    const int p = tid - 5;
    const int gn = min(ccum[p], Kc[p]);
    const float gf = (float)gn;
    const float dd = __fsub_rn(gf, expnf[p]);
    const float imb = __fdiv_rn(__fmul_rn(dd, dd), expnf[p]);
    atomicAdd(&accA[p * 4 + b], (double)imb / (double)gf);
  }

  // ---- fused finalize: last group block computes the loss ----
  __syncthreads();  // drains vmcnt -> this block's atomics are at L2
  if (tid == 0) {
    __threadfence();
    const unsigned int old = atomicAdd(&ctr[CTR_DONE], 1u);
    sm.g.islast = (old == (unsigned int)(N_GROUPS - 1)) ? 1 : 0;
  }
  __syncthreads();
  if (sm.g.islast) {
    if (tid < 25) {
      // device-scope atomic read (add 0.0) -> sees all blocks' additions
      double* src = (tid < 5) ? &totS[tid] : &accA[tid - 5];
      fin[tid] = atomicAdd(src, 0.0);
    }
    __syncthreads();
    if (tid < B_SZ) {
      double acc = 0.0;
#pragma unroll
      for (int p = 0; p < 5; ++p)
        acc += fin[p] * (fin[5 + p * 4 + tid] / (double)SEED_NUM);
      out[tid] = (float)(acc / 5.0);
    }
  }
}

extern "C" void kernel_launch(void* const* d_in, const int* in_sizes, int n_in,
                              void* d_out, int out_size, void* d_ws,
                              size_t ws_size, hipStream_t stream) {
  (void)in_sizes; (void)n_in; (void)out_size; (void)ws_size;
  const float* pcs = (const float*)d_in[0];
  float* out = (float*)d_out;

  // ws layout: seeds (19632 B) | sums (25 doubles, 200 B) | pad |
  // ctr (padded u32 counters, 768 B, 128-aligned at 19840).
  float* seeds = (float*)d_ws;
  double* sums = (double*)((char*)d_ws + 19632);
  unsigned int* ctr = (unsigned int*)((char*)d_ws + 19840);

  // zero sums + counters every invocation (graph-capturable stream op)
  hipMemsetAsync((char*)d_ws + 19632, 0, 976, stream);
  fused_kernel<<<B_SZ + N_GROUPS, THREADS, 0, stream>>>(pcs, seeds, sums, ctr,
                                                        out);
}

// Round 8
// 399.712 us; speedup vs baseline: 1.1984x; 1.1111x over previous
//
#include <hip/hip_runtime.h>
#include <math.h>

#define N_PTS 8192
#define B_SZ 4
#define SEED_NUM 409
#define THREADS 256
#define LTOT 653  // 65+98+131+163+196
#define N_GROUPS (B_SZ * SEED_NUM)
#define PUB 16     // seed publish round (power of 2)
#define NROUND 26  // 25 full rounds of 16 + final round of 9

// padded counter layout (u32 indices): 128 B apart
#define CTR_ROLE 0
#define CTR_DONE 32
#define CTR_PROG(b) (64 + 32 * (b))

typedef float f2 __attribute__((ext_vector_type(2)));
typedef float f4 __attribute__((ext_vector_type(4)));

// Exact IEEE f32 squared distance, same op order as the reference:
// ((dx*dx + dy*dy) + dz*dz), no FMA contraction.
__device__ __forceinline__ float sqdist(float ax, float ay, float az,
                                        float bx, float by, float bz) {
  float dx = __fsub_rn(ax, bx);
  float dy = __fsub_rn(ay, by);
  float dz = __fsub_rn(az, bz);
  return __fadd_rn(__fadd_rn(__fmul_rn(dx, dx), __fmul_rn(dy, dy)),
                   __fmul_rn(dz, dz));
}

#define FOR16(M) \
  M(0) M(1) M(2) M(3) M(4) M(5) M(6) M(7) \
  M(8) M(9) M(10) M(11) M(12) M(13) M(14) M(15)

// u64 lane-move via two 32-bit DPP ops (ctrl fields must be constant
// expressions -> template params). shr-stages: bound_ctrl=1 (OOB lanes
// read 0 — harmless for max of non-negative keys). bcast stages keep `old`
// in masked-off rows so the subsequent max is a no-op there.
template <int CTRL>
__device__ __forceinline__ unsigned long long dpp_u64_bc1(
    unsigned long long k) {
  const unsigned lo2 = (unsigned)__builtin_amdgcn_update_dpp(
      0, (int)(unsigned)k, CTRL, 0xf, 0xf, true);
  const unsigned hi2 = (unsigned)__builtin_amdgcn_update_dpp(
      0, (int)(unsigned)(k >> 32), CTRL, 0xf, 0xf, true);
  return ((unsigned long long)hi2 << 32) | lo2;
}
template <int CTRL, int ROW_MASK>
__device__ __forceinline__ unsigned long long dpp_u64_keep(
    unsigned long long k) {
  const unsigned lo2 = (unsigned)__builtin_amdgcn_update_dpp(
      (int)(unsigned)k, (int)(unsigned)k, CTRL, ROW_MASK, 0xf, false);
  const unsigned hi2 = (unsigned)__builtin_amdgcn_update_dpp(
      (int)(unsigned)(k >> 32), (int)(unsigned)(k >> 32), CTRL, ROW_MASK, 0xf,
      false);
  return ((unsigned long long)hi2 << 32) | lo2;
}

// LDS union: FPS role needs 136 KB; group role ~21 KB.
struct FpsSmem {
  f4 spts4[N_PTS];               // 128 KiB winner-coord broadcast
  float seedbuf[SEED_NUM * 3];   // published-seed staging
  unsigned long long red[2][4];
};
struct GrpSmem {
  f4 tmp[LTOT];   // pass-1 survivors (x,y,z,tier)
  f4 lpt[LTOT];   // bucket-ordered points
  int tcnt[5], tbase[5], bcnt[5], ccum[5];
  int ntmp, capped;
  int wtot[4];
  double wsum[5][4];
  float ssd[3];
  int islast;
};
union SmemU {
  FpsSmem f;
  GrpSmem g;
};

// ---------------------------------------------------------------------------
// R18: two fixes isolated from R17's counters (kernel 411.9 vs fps-solo 333;
// total-kernel gap 32us):
//  (1) STRIP-MINED producer: the publish branch lived INSIDE the sacred R10
//      loop (ledger: any in-loop text change costs +40..+420 cy/iter). Now:
//      outer loop over 26 rounds, inner 16-iter loop is the BYTE-IDENTICAL
//      R10 body; publish/release only at round boundaries. Release for
//      rounds <= r-2 is stored BEFORE issuing round r-1's swaps: vmcnt is
//      already 0 (prior rounds' barriers drained it) -> release waitcnt is
//      free; the fresh swaps drain inside round r's first barrier.
//  (2) hipMemsetAsync -> zero_kernel dispatch: the memset packet cost ~30us
//      per replay (pipeline-drain class); a 1-block kernel is a normal ~2us
//      dispatch (R15's two-kernel gap was ~0).
// Worker/finalize paths unchanged from R17.
// ---------------------------------------------------------------------------
__global__ void zero_kernel(unsigned int* __restrict__ w /*244 words*/) {
  const int t = threadIdx.x;
  if (t < 244) w[t] = 0u;
}

__global__ __launch_bounds__(THREADS, 1) void fused_kernel(
    const float* __restrict__ pcs, float* __restrict__ seeds,
    double* __restrict__ sums /* totS[5] + accA[20] */,
    unsigned int* __restrict__ ctr /* padded, see CTR_* */,
    float* __restrict__ out) {
#pragma clang fp contract(off)
  const int tid = threadIdx.x;
  __shared__ SmemU sm;
  __shared__ int roleS;
  __shared__ double fin[25];

  if (tid == 0) roleS = (int)atomicAdd(&ctr[CTR_ROLE], 1u);
  __syncthreads();
  const int role = roleS;

  if (role < B_SZ) {
    // =============================== FPS ===================================
    const int b = role;
    const int lane = tid & 63, wid = tid >> 6;  // 4 waves
    const float* base = pcs + (size_t)b * N_PTS * 3;
    f4* spts4 = sm.f.spts4;
    float* seedbuf = sm.f.seedbuf;
    auto& red = sm.f.red;
    float* sgb = seeds + (size_t)b * SEED_NUM * 3;

    // pair j holds points i0 = tid + (2j)*256 and i1 = tid + (2j+1)*256
#define FPS_DECL(j) f2 px##j, py##j, pz##j, md##j;
    FOR16(FPS_DECL)
#undef FPS_DECL

#define FPS_INIT(j)                                   \
  {                                                   \
    const int i0 = tid + (2 * (j)) * THREADS;         \
    const int i1 = i0 + THREADS;                      \
    px##j = (f2){base[i0 * 3 + 0], base[i1 * 3 + 0]}; \
    py##j = (f2){base[i0 * 3 + 1], base[i1 * 3 + 1]}; \
    pz##j = (f2){base[i0 * 3 + 2], base[i1 * 3 + 2]}; \
    md##j = (f2){1e10f, 1e10f}; /* ref 1e10 exact */  \
    spts4[i0] = (f4){px##j.x, py##j.x, pz##j.x, 0.f}; \
    spts4[i1] = (f4){px##j.y, py##j.y, pz##j.y, 0.f}; \
  }
    FOR16(FPS_INIT)
#undef FPS_INIT

    // Pin coords in VGPRs (asm results can't be rematerialized from memory).
#define FPS_PIN(j) asm volatile("" : "+v"(px##j), "+v"(py##j), "+v"(pz##j));
    FOR16(FPS_PIN)
#undef FPS_PIN

    float cx = base[0], cy = base[1], cz = base[2];

    for (int r = 0; r < NROUND; ++r) {
      // release rounds <= r-2 (swaps long drained -> waitcnt free). MUST
      // precede this round's publish swaps, else the release would wait on
      // them.
      if (r > 1 && tid == 0) {
        __hip_atomic_store(&ctr[CTR_PROG(b)], (unsigned)((r - 1) * PUB),
                           __ATOMIC_RELEASE, __HIP_MEMORY_SCOPE_AGENT);
      }
      // publish round r-1's 16 seeds: one wave-wide swap, fire-and-forget;
      // drains inside this round's first iteration barrier.
      if (r > 0 && tid < PUB * 3) {
        const int s0 = (r - 1) * PUB;
        const float v = seedbuf[s0 * 3 + tid];
        atomicExch(&sgb[s0 * 3 + tid], v);
      }
      const int send = (r == NROUND - 1) ? SEED_NUM : (r * PUB + PUB);
      for (int s = r * PUB; s < send; ++s) {
        if (tid == 0) {
          seedbuf[s * 3 + 0] = cx;
          seedbuf[s * 3 + 1] = cy;
          seedbuf[s * 3 + 2] = cz;
        }
        const f2 ccx = (f2){cx, cx}, ccy = (f2){cy, cy}, ccz = (f2){cz, cz};
        float bv = -1.0f;
        int bi = 0;
        // ascending index order + strict '>' keeps the first index on ties.
#define FPS_UPD(j)                                                  \
  {                                                                 \
    const f2 dx = px##j - ccx;                                      \
    const f2 dy = py##j - ccy;                                      \
    const f2 dz = pz##j - ccz;                                      \
    const f2 t0 = dx * dx;                                          \
    const f2 t1 = dy * dy;                                          \
    const f2 t2 = dz * dz;                                          \
    const f2 d2 = (t0 + t1) + t2;                                   \
    const f2 m = __builtin_elementwise_min(md##j, d2);              \
    md##j = m;                                                      \
    if (m.x > bv) { bv = m.x; bi = tid + (2 * (j)) * THREADS; }     \
    if (m.y > bv) { bv = m.y; bi = tid + (2 * (j) + 1) * THREADS; } \
  }
        FOR16(FPS_UPD)
#undef FPS_UPD
        // packed argmax key: bv >= 0 so f32 bits are monotone; u64 max ==
        // (max value, tie -> min index) == jnp.argmax semantics.
        unsigned long long key =
            ((unsigned long long)__float_as_uint(bv) << 32) |
            (unsigned long long)(unsigned)(N_PTS - 1 - bi);
        unsigned long long o;
        o = dpp_u64_bc1<0x111>(key);        key = (o > key) ? o : key;
        o = dpp_u64_bc1<0x112>(key);        key = (o > key) ? o : key;
        o = dpp_u64_bc1<0x114>(key);        key = (o > key) ? o : key;
        o = dpp_u64_bc1<0x118>(key);        key = (o > key) ? o : key;
        o = dpp_u64_keep<0x142, 0xa>(key);  key = (o > key) ? o : key;
        o = dpp_u64_keep<0x143, 0xc>(key);  key = (o > key) ? o : key;
        if (lane == 63) red[s & 1][wid] = key;
        __syncthreads();
        unsigned long long kmax = red[s & 1][0];
#pragma unroll
        for (int w = 1; w < 4; ++w) {
          const unsigned long long t = red[s & 1][w];
          kmax = (t > kmax) ? t : kmax;
        }
        const int ci = N_PTS - 1 - (int)(unsigned)(kmax & 0xffffffffull);
        const f4 c = spts4[ci];  // one ds_read_b128, same-address broadcast
        cx = c.x;
        cy = c.y;
        cz = c.z;
      }
    }

    // tail: round 24 (s 384..399) was published at r=25; publish round 25
    // (s 400..408, 27 floats), drain, release everything.
    {
      const int s0 = (NROUND - 1) * PUB;    // 400
      const int nfl = (SEED_NUM - s0) * 3;  // 27
      if (tid < nfl) {
        const float v = seedbuf[s0 * 3 + tid];
        atomicExch(&sgb[s0 * 3 + tid], v);
      }
      __syncthreads();  // drains all outstanding swaps
      if (tid == 0)
        __hip_atomic_store(&ctr[CTR_PROG(b)], (unsigned)SEED_NUM,
                           __ATOMIC_RELEASE, __HIP_MEMORY_SCOPE_AGENT);
    }
    return;
  }

  // ============================ GROUP worker ===============================
  const int tk = role - B_SZ;
  if (tk >= N_GROUPS) return;
  const int s = tk >> 2;   // ascending ticket -> ascending seed
  const int b = tk & 3;
  const int lane = tid & 63, wid = tid >> 6;

  const int Kc[5] = {65, 98, 131, 163, 196};
  const int off[5] = {0, 65, 163, 294, 457};  // fallback layout only
  const double Pd[5] = {0.004, 0.006, 0.008, 0.01, 0.012};
  float r2c[5], expnf[5], expdc[5];
#pragma unroll
  for (int p = 0; p < 5; ++p) {
    const double pd = Pd[p];
    const double rd = sqrt(pd);
    r2c[p] = (float)(rd * rd);                     // weak f32 cast of r*r
    const double expn_d = 8192.0 * pd;
    expnf[p] = (float)expn_d;
    expdc[p] = sqrtf((float)(M_PI / expn_d * pd));  // expect_dis
  }

  const float* base = pcs + (size_t)b * N_PTS * 3;
  f4* tmp = sm.g.tmp;
  f4* lpt = sm.g.lpt;
  int* tcnt = sm.g.tcnt;
  int* tbase = sm.g.tbase;
  int* bcnt = sm.g.bcnt;
  int* ccum = sm.g.ccum;
  int* wtot = sm.g.wtot;
  double (*wsum)[4] = sm.g.wsum;
  double* totS = sums;
  double* accA = sums + 5;

  if (tid < 5) { tcnt[tid] = 0; bcnt[tid] = 0; }
  if (tid == 6) sm.g.ntmp = 0;
  if (tid == 0) {
    // wait for seed s of batch b, then device-coherent RMW read
    while (__hip_atomic_load(&ctr[CTR_PROG(b)], __ATOMIC_ACQUIRE,
                             __HIP_MEMORY_SCOPE_AGENT) <= (unsigned)s)
      __builtin_amdgcn_s_sleep(32);
    const size_t so = ((size_t)b * SEED_NUM + s) * 3;
    sm.g.ssd[0] = atomicAdd(&seeds[so + 0], 0.0f);  // returns OLD: exact
    sm.g.ssd[1] = atomicAdd(&seeds[so + 1], 0.0f);
    sm.g.ssd[2] = atomicAdd(&seeds[so + 2], 0.0f);
  }
  __syncthreads();
  const float sx = sm.g.ssd[0], sy = sm.g.ssd[1], sz = sm.g.ssd[2];

  // ---- pass 1: vectorized scan, tier-count + unordered survivor append ----
  const float r2max = r2c[4];
  const f4* base4 = (const f4*)base;  // 12B-packed points, 16B-aligned base
#define PROC(X, Y, Z)                                              \
  {                                                                \
    const float d2 = sqdist((X), (Y), (Z), sx, sy, sz);            \
    if (d2 < r2max) {                                              \
      const int tier = (d2 < r2c[0]) ? 0                           \
                       : (d2 < r2c[1]) ? 1                         \
                       : (d2 < r2c[2]) ? 2                         \
                       : (d2 < r2c[3]) ? 3 : 4;                    \
      atomicAdd(&tcnt[tier], 1);                                   \
      const int pos = atomicAdd(&sm.g.ntmp, 1);                    \
      if (pos < LTOT) tmp[pos] = (f4){(X), (Y), (Z), (float)tier}; \
    }                                                              \
  }
  for (int it = 0; it < 8; ++it) {
    const int q = it * 256 + tid;  // quad-of-points index, 0..2047
    const f4 v0 = base4[q * 3 + 0];
    const f4 v1 = base4[q * 3 + 1];
    const f4 v2 = base4[q * 3 + 2];
    PROC(v0.x, v0.y, v0.z)
    PROC(v0.w, v1.x, v1.y)
    PROC(v1.z, v1.w, v2.x)
    PROC(v2.y, v2.z, v2.w)
  }
#undef PROC
  __syncthreads();

  // ---- prefix + cap check ----
  if (tid == 0) {
    int acc = 0, cap = 0;
#pragma unroll
    for (int t = 0; t < 5; ++t) {
      tbase[t] = acc;
      acc += tcnt[t];
      ccum[t] = acc;
    }
#pragma unroll
    for (int p = 0; p < 5; ++p) cap |= (ccum[p] > Kc[p]) ? 1 : 0;
    sm.g.capped = cap;
  }
  __syncthreads();

  // ---- pass 2: scatter survivors to tier-bucket positions ----
  const int nt = min(sm.g.ntmp, LTOT);
  for (int t = tid; t < nt; t += 256) {
    const f4 e = tmp[t];
    const int tier = (int)e.w;
    const int pos = tbase[tier] + atomicAdd(&bcnt[tier], 1);
    if (pos < LTOT) lpt[pos] = (f4){e.x, e.y, e.z, 0.f};
  }
  __syncthreads();

  if (!sm.g.capped) {
    // ---- segmented KNN: one pass over [0, c4) per row, snapshots at
    //      bucket boundaries give the two-min of every prefix list ----
    const int c0 = ccum[0], c1 = ccum[1], c2 = ccum[2], c3 = ccum[3],
              c4 = ccum[4];
    double lS0 = 0.0, lS1 = 0.0, lS2 = 0.0, lS3 = 0.0, lS4 = 0.0;
    for (int r0 = 0; r0 < c4; r0 += 64) {
      const int row = r0 + (tid >> 2);
      const int sub = tid & 3;
      const bool rok = row < c4;
      const f4 pi = lpt[rok ? row : 0];
      float m1 = INFINITY, m2 = INFINITY;
      int j = sub;
#define SEGMENT(CP, EDP, LSP)                                        \
  {                                                                  \
    for (; j < (CP); j += 4) {                                       \
      const f4 pj = lpt[j];                                          \
      const float d2 = sqdist(pi.x, pi.y, pi.z, pj.x, pj.y, pj.z);   \
      if (d2 < m1) { m2 = m1; m1 = d2; }                             \
      else if (d2 < m2) { m2 = d2; }                                 \
    }                                                                \
    float s1 = m1, s2 = m2;                                          \
    {                                                                \
      const float o1 = __shfl_xor(s1, 1), o2 = __shfl_xor(s2, 1);    \
      const float lo = fminf(s1, o1), hi = fmaxf(s1, o1);            \
      s2 = fminf(fminf(s2, o2), hi); s1 = lo;                        \
    }                                                                \
    {                                                                \
      const float o1 = __shfl_xor(s1, 2), o2 = __shfl_xor(s2, 2);    \
      const float lo = fminf(s1, o1), hi = fmaxf(s1, o1);            \
      s2 = fminf(fminf(s2, o2), hi); s1 = lo;                        \
    }                                                                \
    if (rok && sub == 0 && row < (CP)) {                             \
      const float nn2 = (s2 > 1e37f) ? 0.0f : s2; /* inf -> 0 */     \
      const float nnd = (nn2 > 0.0f) ? sqrtf(nn2) : 0.0f;            \
      const float diff = __fsub_rn(nnd, (EDP));                      \
      const float clut = __fdiv_rn(__fmul_rn(diff, diff),            \
                                   __fadd_rn((EDP), 1e-12f));        \
      LSP += (double)clut;                                           \
    }                                                                \
  }
      SEGMENT(c0, expdc[0], lS0)
      SEGMENT(c1, expdc[1], lS1)
      SEGMENT(c2, expdc[2], lS2)
      SEGMENT(c3, expdc[3], lS3)
      SEGMENT(c4, expdc[4], lS4)
#undef SEGMENT
    }
#define RED(LSP, P)                                          \
  {                                                          \
    double v = (LSP);                                        \
    for (int o = 32; o > 0; o >>= 1) v += __shfl_down(v, o); \
    if (lane == 0) wsum[(P)][wid] = v;                       \
  }
    RED(lS0, 0) RED(lS1, 1) RED(lS2, 2) RED(lS3, 3) RED(lS4, 4)
#undef RED
  } else {
    // ---- measure-zero fallback: ordered per-p lists + old per-p KNN ----
#pragma unroll
    for (int p = 0; p < 5; ++p) {
      int run = 0;
      for (int base_i = 0; base_i < N_PTS; base_i += 256) {
        const int i = base_i + tid;
        const float x = base[i * 3 + 0];
        const float y = base[i * 3 + 1];
        const float z = base[i * 3 + 2];
        const float d2 = sqdist(x, y, z, sx, sy, sz);
        const bool valid = d2 < r2c[p];
        const unsigned long long m = __ballot(valid);
        if (lane == 0) wtot[wid] = __popcll(m);
        __syncthreads();
        int pos = run + __popcll(m & ((1ull << lane) - 1ull));
        for (int w = 0; w < wid; ++w) pos += wtot[w];
        if (valid && pos < Kc[p]) {
          lpt[off[p] + pos] = (f4){x, y, z, 0.f};
        }
        run += wtot[0] + wtot[1] + wtot[2] + wtot[3];
        __syncthreads();
      }
    }
#pragma unroll
    for (int p = 0; p < 5; ++p) {
      const int gn = min(ccum[p], Kc[p]);
      const float ed = expdc[p];
      const int lb = off[p];
      double localS = 0.0;
      for (int r0 = 0; r0 < gn; r0 += 64) {
        const int row = r0 + (tid >> 2);
        const int sub = tid & 3;
        float m1 = INFINITY, m2 = INFINITY;
        if (row < gn) {
          const f4 pi = lpt[lb + row];
          for (int j = sub; j < gn; j += 4) {
            const f4 pj = lpt[lb + j];
            const float d2 = sqdist(pi.x, pi.y, pi.z, pj.x, pj.y, pj.z);
            if (d2 < m1) { m2 = m1; m1 = d2; }
            else if (d2 < m2) { m2 = d2; }
          }
        }
#pragma unroll
        for (int d = 1; d <= 2; d <<= 1) {
          const float om1 = __shfl_xor(m1, d);
          const float om2 = __shfl_xor(m2, d);
          const float lo = fminf(m1, om1);
          const float hi = fmaxf(m1, om1);
          m2 = fminf(fminf(m2, om2), hi);
          m1 = lo;
        }
        if (row < gn && sub == 0) {
          const float nn2 = (m2 > 1e37f) ? 0.0f : m2;
          const float nnd = (nn2 > 0.0f) ? sqrtf(nn2) : 0.0f;
          const float diff = __fsub_rn(nnd, ed);
          const float clut = __fdiv_rn(__fmul_rn(diff, diff),
                                       __fadd_rn(ed, 1e-12f));
          localS += (double)clut;
        }
      }
#pragma unroll
      for (int o = 32; o > 0; o >>= 1) localS += __shfl_down(localS, o);
      if (lane == 0) wsum[p][wid] = localS;
      __syncthreads();
    }
  }
  __syncthreads();

  // 10 parallel device atomics: threads 0-4 -> totS, threads 5-9 -> accA.
  if (tid < 5) {
    const double S = wsum[tid][0] + wsum[tid][1] + wsum[tid][2] + wsum[tid][3];
    atomicAdd(&totS[tid], S);
  } else if (tid < 10) {
    const int p = tid - 5;
    const int gn = min(ccum[p], Kc[p]);
    const float gf = (float)gn;
    const float dd = __fsub_rn(gf, expnf[p]);
    const float imb = __fdiv_rn(__fmul_rn(dd, dd), expnf[p]);
    atomicAdd(&accA[p * 4 + b], (double)imb / (double)gf);
  }

  // ---- fused finalize: last group block computes the loss ----
  __syncthreads();  // drains vmcnt -> this block's atomics are at L2
  if (tid == 0) {
    __threadfence();
    const unsigned int old = atomicAdd(&ctr[CTR_DONE], 1u);
    sm.g.islast = (old == (unsigned int)(N_GROUPS - 1)) ? 1 : 0;
  }
  __syncthreads();
  if (sm.g.islast) {
    if (tid < 25) {
      // device-scope atomic read (add 0.0) -> sees all blocks' additions
      double* src = (tid < 5) ? &totS[tid] : &accA[tid - 5];
      fin[tid] = atomicAdd(src, 0.0);
    }
    __syncthreads();
    if (tid < B_SZ) {
      double acc = 0.0;
#pragma unroll
      for (int p = 0; p < 5; ++p)
        acc += fin[p] * (fin[5 + p * 4 + tid] / (double)SEED_NUM);
      out[tid] = (float)(acc / 5.0);
    }
  }
}

extern "C" void kernel_launch(void* const* d_in, const int* in_sizes, int n_in,
                              void* d_out, int out_size, void* d_ws,
                              size_t ws_size, hipStream_t stream) {
  (void)in_sizes; (void)n_in; (void)out_size; (void)ws_size;
  const float* pcs = (const float*)d_in[0];
  float* out = (float*)d_out;

  // ws layout: seeds (19632 B) | sums (25 doubles, 200 B) | pad |
  // ctr (padded u32 counters, 768 B, 128-aligned at 19840).
  float* seeds = (float*)d_ws;
  double* sums = (double*)((char*)d_ws + 19632);
  unsigned int* ctr = (unsigned int*)((char*)d_ws + 19840);

  // zero sums+ctr (244 u32 words) via a normal dispatch — hipMemsetAsync's
  // packet cost ~30us/replay (R16/R17: total-kernel gap 32us vs R15's ~0).
  zero_kernel<<<1, 256, 0, stream>>>((unsigned int*)((char*)d_ws + 19632));
  fused_kernel<<<B_SZ + N_GROUPS, THREADS, 0, stream>>>(pcs, seeds, sums, ctr,
                                                        out);
}